// Round 2
// baseline (570.637 us; speedup 1.0000x reference)
//
#include <hip/hip_runtime.h>
#include <hip/hip_fp16.h>

// Hyperbolic GCN layer, c = 1.0
// x [N,D] f32, W [D,D] f32, edge_vals [E] f32, rows [E] i32, cols [E] i32 -> out [N,D] f32
//
// *** ROUND-14: DIAGNOSTIC BUILD ***
// sortgather_kernel body repeated REP_SG=16x (idempotent) to (a) lift its
// per-dispatch duration above the ~44us fillBuffer resets so it appears in the
// top-5 rocprof table with full counters, and (b) measure its true share:
//     t_sortgather = (dur_us - 147) / 15.
// All other kernels byte-identical to round-13 (147.1 us baseline).
//
// Algebraic note (verified vs reference): with sc=1,
//   logmap0(mobius_matvec(W,x)) = (atanh(||x||)/||x||) * (W x)      [atanh∘tanh cancels]
//   relu(logmap0(expmap0(s)))   = relu(s)                           [logmap0∘expmap0 = id]
//
// Forbidden patterns (measured): scattered per-lane LDS float atomics (R3: 557us,
// R15: 538us); serial chained global atomics for range reservation (R8: 86us stall).
#define NN 100000
#define DD 64
#define EE 1600000
#define NB 512          // node buckets == sort chunks
#define NPB 196         // nodes per bucket (NB*NPB = 100352 >= NN)
#define CHUNK 3125      // edges per chunk (CHUNK * NB == EE)
#define CAP 3520        // per-bucket LDS capacity (mean 3125, sigma ~56 -> +7 sigma)
#define REP_SG 16       // DIAGNOSTIC repetition of sortgather body

typedef _Float16 half8 __attribute__((ext_vector_type(8)));
typedef float floatx4 __attribute__((ext_vector_type(4)));

__device__ __forceinline__ float frcp(float x) { return __builtin_amdgcn_rcpf(x); }

__device__ __forceinline__ float fast_tanh(float x) {           // x >= 0 here
    float t = __expf(2.0f * x);
    return (t - 1.0f) * frcp(t + 1.0f);
}
__device__ __forceinline__ float fast_atanh(float x) {
    const float CLIP = 1.0f - 1e-7f;
    x = fminf(fmaxf(x, -CLIP), CLIP);
    return 0.5f * __logf((1.0f + x) * frcp(1.0f - x));
}
__device__ __forceinline__ float group16_reduce_sum(float v) {
    #pragma unroll
    for (int m = 8; m > 0; m >>= 1) v += __shfl_xor(v, m, 16);
    return v;
}
__device__ __forceinline__ float lo16f(unsigned u) {
    return __half2float(__ushort_as_half((unsigned short)(u & 0xFFFFu)));
}
__device__ __forceinline__ float hi16f(unsigned u) {
    return __half2float(__ushort_as_half((unsigned short)(u >> 16)));
}

// ---- Stage 1 (MFMA) + per-chunk bucket counts ----
__global__ __launch_bounds__(1024) void linear_count_kernel(
    const float* __restrict__ x, const float* __restrict__ W,
    const int* __restrict__ rows,
    __half* __restrict__ hidden, int* __restrict__ cnt) {
    __shared__ _Float16 Wh[64 * 80];   // stride 80 halves keeps b128 aligned
    __shared__ int h[NB];
    const int t = threadIdx.x;

    if (t < NB) h[t] = 0;
    for (int i = t; i < 64 * 64; i += 1024)
        Wh[(i >> 6) * 80 + (i & 63)] = (_Float16)W[i];
    __syncthreads();

    {   // histogram this chunk (LDS atomics on 512 int counters only)
        const int e0 = blockIdx.x * CHUNK;
        for (int i = t; i < CHUNK; i += 1024)
            atomicAdd(&h[(unsigned)rows[e0 + i] / NPB], 1);
    }

    const int lane = t & 63;
    const int wv   = t >> 6;             // waves 0..12 do MFMA (13*16=208 nodes)
    if (wv < 13) {
        const int q    = lane >> 4;
        const int c    = lane & 15;
        const int node = blockIdx.x * NPB + wv * 16 + c;
        const int node_ld = (node < NN) ? node : (NN - 1);

        const float MIN_NORM = 1e-15f;
        const float4* xr = (const float4*)(x + node_ld * 64);
        float4 b0a = xr[q * 2];
        float4 b0b = xr[q * 2 + 1];
        float4 b1a = xr[8 + q * 2];
        float4 b1b = xr[8 + q * 2 + 1];

        float xpart = b0a.x*b0a.x + b0a.y*b0a.y + b0a.z*b0a.z + b0a.w*b0a.w
                    + b0b.x*b0b.x + b0b.y*b0b.y + b0b.z*b0b.z + b0b.w*b0b.w
                    + b1a.x*b1a.x + b1a.y*b1a.y + b1a.z*b1a.z + b1a.w*b1a.w
                    + b1b.x*b1b.x + b1b.y*b1b.y + b1b.z*b1b.z + b1b.w*b1b.w;
        xpart += __shfl_xor(xpart, 16, 64);
        xpart += __shfl_xor(xpart, 32, 64);
        float x_n = fmaxf(sqrtf(xpart), MIN_NORM);

        half8 bf0, bf1;
        bf0[0]=(_Float16)b0a.x; bf0[1]=(_Float16)b0a.y; bf0[2]=(_Float16)b0a.z; bf0[3]=(_Float16)b0a.w;
        bf0[4]=(_Float16)b0b.x; bf0[5]=(_Float16)b0b.y; bf0[6]=(_Float16)b0b.z; bf0[7]=(_Float16)b0b.w;
        bf1[0]=(_Float16)b1a.x; bf1[1]=(_Float16)b1a.y; bf1[2]=(_Float16)b1a.z; bf1[3]=(_Float16)b1a.w;
        bf1[4]=(_Float16)b1b.x; bf1[5]=(_Float16)b1b.y; bf1[6]=(_Float16)b1b.z; bf1[7]=(_Float16)b1b.w;

        floatx4 acc[4];
        #pragma unroll
        for (int tt = 0; tt < 4; ++tt) {
            const half8* a0 = (const half8*)&Wh[(16 * tt + c) * 80 + q * 8];
            const half8* a1 = (const half8*)&Wh[(16 * tt + c) * 80 + 32 + q * 8];
            floatx4 z = {0.f, 0.f, 0.f, 0.f};
            z = __builtin_amdgcn_mfma_f32_16x16x32_f16(a0[0], bf0, z, 0, 0, 0);
            z = __builtin_amdgcn_mfma_f32_16x16x32_f16(a1[0], bf1, z, 0, 0, 0);
            acc[tt] = z;
        }

        float hscale = fast_atanh(x_n) * frcp(x_n);

        if (node < NN) {
            #pragma unroll
            for (int tt = 0; tt < 4; ++tt) {
                __half2 lo = __floats2half2_rn(acc[tt][0] * hscale, acc[tt][1] * hscale);
                __half2 hi = __floats2half2_rn(acc[tt][2] * hscale, acc[tt][3] * hscale);
                uint2 pkt;
                pkt.x = *(unsigned*)&lo;
                pkt.y = *(unsigned*)&hi;
                ((uint2*)hidden)[node * 16 + tt * 4 + q] = pkt;
            }
        }
    }
    __syncthreads();
    if (t < NB) cnt[blockIdx.x * NB + t] = h[t];   // coalesced row write
}

// ---- Per-bucket exclusive scan over chunk counts -> woff + bucket totals ----
__global__ __launch_bounds__(512) void offset_kernel(const int* __restrict__ cnt,
                                                     int* __restrict__ woff,
                                                     int* __restrict__ gcount) {
    const int lane = threadIdx.x & 63;
    const int b    = blockIdx.x * 8 + (threadIdx.x >> 6);   // bucket
    int c[8]; int sum = 0;
    #pragma unroll
    for (int k = 0; k < 8; ++k) { c[k] = cnt[(lane * 8 + k) * NB + b]; sum += c[k]; }
    int pre = sum;
    #pragma unroll
    for (int m = 1; m < 64; m <<= 1) {
        int u = __shfl_up(pre, m, 64);
        if (lane >= m) pre += u;
    }
    int run = pre - sum;
    #pragma unroll
    for (int k = 0; k < 8; ++k) { woff[(lane * 8 + k) * NB + b] = run; run += c[k]; }
    if (lane == 63) gcount[b] = run;   // bucket total
}

// ---- Local counting sort + coalesced scatter. Counts precomputed; deterministic
//      offsets, no global atomics. Bucket-base scan recomputed per block. ----
// payload: word0 = rl<<24 | col*128 (byte offset into fp16 hidden rows), word1 = val fp32
__global__ __launch_bounds__(1024, 8) void sort_scatter_kernel(
    const int* __restrict__ rows, const int* __restrict__ cols,
    const float* __restrict__ ev, const int* __restrict__ cnt,
    const int* __restrict__ woff, const int* __restrict__ gcount,
    int2* __restrict__ csr) {
    __shared__ int cur[NB];
    __shared__ int delta[NB];
    __shared__ int2 sorted[CHUNK];
    __shared__ unsigned short bid[CHUNK];
    const int t  = threadIdx.x;
    const int e0 = blockIdx.x * CHUNK;

    if (t < 64) {
        const int lane = t;
        // exclusive scan of gcount -> bucket bases (redundant per block, cheap)
        int g[8]; int gsum = 0;
        #pragma unroll
        for (int k = 0; k < 8; ++k) { g[k] = gcount[lane * 8 + k]; gsum += g[k]; }
        int gpre = gsum;
        #pragma unroll
        for (int m = 1; m < 64; m <<= 1) {
            int u = __shfl_up(gpre, m, 64);
            if (lane >= m) gpre += u;
        }
        int grun = gpre - gsum;                    // bbase[lane*8]
        // chunk-local counting-sort offsets
        int c[8]; int sum = 0;
        #pragma unroll
        for (int k = 0; k < 8; ++k) { c[k] = cnt[blockIdx.x * NB + lane * 8 + k]; sum += c[k]; }
        int pre = sum;
        #pragma unroll
        for (int m = 1; m < 64; m <<= 1) {
            int u = __shfl_up(pre, m, 64);
            if (lane >= m) pre += u;
        }
        int run = pre - sum;
        #pragma unroll
        for (int k = 0; k < 8; ++k) {
            int b = lane * 8 + k;
            cur[b]   = run;                                  // LDS scatter cursor
            delta[b] = grun + woff[blockIdx.x * NB + b] - run; // LDS pos -> global
            grun += g[k];
            run  += c[k];
        }
    }
    __syncthreads();
    for (int i = t; i < CHUNK; i += 1024) {
        unsigned r = (unsigned)rows[e0 + i];
        unsigned c = (unsigned)cols[e0 + i];
        float v = ev[e0 + i];
        unsigned b  = r / NPB;
        unsigned rl = r - b * NPB;
        int idx = atomicAdd(&cur[b], 1);
        sorted[idx] = make_int2((int)((rl << 24) | (c << 7)), __float_as_int(v));
        bid[idx] = (unsigned short)b;
    }
    __syncthreads();
    for (int i = t; i < CHUNK; i += 1024) {
        int2 eV = sorted[i];
        csr[delta[bid[i]] + i] = eV;
    }
}

// ---- Fused: stage csr segment into LDS once (histogram fused into the staging
//      read), per-bucket node counting-sort LDS->LDS, quarter-wave register
//      gather, epilogue out = proj(expmap0(relu(support))).
//      DIAGNOSTIC: body repeated REP_SG times (idempotent). ----
__global__ __launch_bounds__(1024, 8) void sortgather_kernel(
    const __half* __restrict__ hidden, const int2* __restrict__ csr,
    const int* __restrict__ gcount, float* __restrict__ out) {
    __shared__ int2 raw[CAP];          // 28,160 B, staged csr segment
    __shared__ int2 srt[CAP];          // 28,160 B, node-sorted descriptors
    __shared__ int cnt_a[NPB];
    __shared__ int start[NPB];
    __shared__ int cur[NPB];
    __shared__ int s_lo, s_cnt;
    const int t  = threadIdx.x;
    const int b  = blockIdx.x;

    if (t < 64) {
        // exclusive scan of gcount; pick out bbase[b] and gcount[b]
        int g[8]; int gsum = 0;
        #pragma unroll
        for (int k = 0; k < 8; ++k) { g[k] = gcount[t * 8 + k]; gsum += g[k]; }
        int gpre = gsum;
        #pragma unroll
        for (int m = 1; m < 64; m <<= 1) {
            int u = __shfl_up(gpre, m, 64);
            if (t >= m) gpre += u;
        }
        int run = gpre - gsum;                 // bbase[t*8]
        #pragma unroll
        for (int k = 0; k < 8; ++k) {
            int bb = t * 8 + k;
            if (bb == b) { s_lo = run; s_cnt = g[k]; }
            run += g[k];
        }
    }
    __syncthreads();
    const int lo  = s_lo;
    int ecnt = s_cnt;
    if (ecnt > CAP) ecnt = CAP;        // statistically unreachable guard

    for (int rep = 0; rep < REP_SG; ++rep) {   // DIAGNOSTIC loop, idempotent
        if (t < NPB) cnt_a[t] = 0;
        __syncthreads();

        for (int i = t; i < ecnt; i += 1024) {       // stage + fused histogram
            int2 e = csr[lo + i];
            raw[i] = e;
            atomicAdd(&cnt_a[((unsigned)e.x) >> 24], 1);
        }
        __syncthreads();
        if (t < 64) {
            const int lane = t;
            int c[4]; int sum = 0;
            #pragma unroll
            for (int k = 0; k < 4; ++k) {
                int bb = lane * 4 + k;
                c[k] = (bb < NPB) ? cnt_a[bb] : 0;
                sum += c[k];
            }
            int pre = sum;
            #pragma unroll
            for (int m = 1; m < 64; m <<= 1) {
                int u = __shfl_up(pre, m, 64);
                if (lane >= m) pre += u;
            }
            int run = pre - sum;
            #pragma unroll
            for (int k = 0; k < 4; ++k) {
                int bb = lane * 4 + k;
                if (bb < NPB) { start[bb] = run; cur[bb] = run; run += c[k]; }
            }
        }
        __syncthreads();
        for (int i = t; i < ecnt; i += 1024) {       // LDS -> LDS counting sort
            int2 e = raw[i];
            int p  = atomicAdd(&cur[((unsigned)e.x) >> 24], 1);
            srt[p] = e;
        }
        __syncthreads();

        const int lane = t & 63;
        const int wv   = t >> 6;               // 0..15
        const int g    = lane >> 4;
        const int l8   = (lane & 15) * 8;
        const char* __restrict__ hidc = (const char*)hidden;
        const float MIN_NORM = 1e-15f;
        const float MAX_N = 1.0f - 1e-5f;

        for (int n = wv; n < NPB; n += 16) {
            int i   = start[n];
            int rhi = i + cnt_a[n];
            float ax = 0.f, ay = 0.f, az = 0.f, aw = 0.f;

            for (; i + 16 <= rhi; i += 16) {         // 4 groups of 4 edges in flight
                int2 dA = srt[i + g];
                int2 dB = srt[i + 4 + g];
                int2 dC = srt[i + 8 + g];
                int2 dD = srt[i + 12 + g];
                unsigned oA = (((unsigned)dA.x) & 0xFFFFFFu) + l8;
                unsigned oB = (((unsigned)dB.x) & 0xFFFFFFu) + l8;
                unsigned oC = (((unsigned)dC.x) & 0xFFFFFFu) + l8;
                unsigned oD = (((unsigned)dD.x) & 0xFFFFFFu) + l8;
                uint2 hA = *(const uint2*)(hidc + oA);
                uint2 hB = *(const uint2*)(hidc + oB);
                uint2 hC = *(const uint2*)(hidc + oC);
                uint2 hD = *(const uint2*)(hidc + oD);
                float vA = __int_as_float(dA.y);
                float vB = __int_as_float(dB.y);
                float vC = __int_as_float(dC.y);
                float vD = __int_as_float(dD.y);
                ax = fmaf(vA, lo16f(hA.x), ax);
                ay = fmaf(vA, hi16f(hA.x), ay);
                az = fmaf(vA, lo16f(hA.y), az);
                aw = fmaf(vA, hi16f(hA.y), aw);
                ax = fmaf(vB, lo16f(hB.x), ax);
                ay = fmaf(vB, hi16f(hB.x), ay);
                az = fmaf(vB, lo16f(hB.y), az);
                aw = fmaf(vB, hi16f(hB.y), aw);
                ax = fmaf(vC, lo16f(hC.x), ax);
                ay = fmaf(vC, hi16f(hC.x), ay);
                az = fmaf(vC, lo16f(hC.y), az);
                aw = fmaf(vC, hi16f(hC.y), aw);
                ax = fmaf(vD, lo16f(hD.x), ax);
                ay = fmaf(vD, hi16f(hD.x), ay);
                az = fmaf(vD, lo16f(hD.y), az);
                aw = fmaf(vD, hi16f(hD.y), aw);
            }
            if (i + 8 <= rhi) {                      // 2 groups of 4 edges
                int2 dA = srt[i + g];
                int2 dB = srt[i + 4 + g];
                unsigned oA = (((unsigned)dA.x) & 0xFFFFFFu) + l8;
                unsigned oB = (((unsigned)dB.x) & 0xFFFFFFu) + l8;
                uint2 hA = *(const uint2*)(hidc + oA);
                uint2 hB = *(const uint2*)(hidc + oB);
                float vA = __int_as_float(dA.y);
                float vB = __int_as_float(dB.y);
                ax = fmaf(vA, lo16f(hA.x), ax);
                ay = fmaf(vA, hi16f(hA.x), ay);
                az = fmaf(vA, lo16f(hA.y), az);
                aw = fmaf(vA, hi16f(hA.y), aw);
                ax = fmaf(vB, lo16f(hB.x), ax);
                ay = fmaf(vB, hi16f(hB.x), ay);
                az = fmaf(vB, lo16f(hB.y), az);
                aw = fmaf(vB, hi16f(hB.y), aw);
                i += 8;
            }
            for (; i < rhi; i += 4) {                // masked 4-edge groups (<=2 iters)
                int idx = i + g;
                int2 d = srt[(idx < rhi) ? idx : (rhi - 1)];
                float v = (idx < rhi) ? __int_as_float(d.y) : 0.0f;
                unsigned o = (((unsigned)d.x) & 0xFFFFFFu) + l8;
                uint2 h = *(const uint2*)(hidc + o);
                ax = fmaf(v, lo16f(h.x), ax);
                ay = fmaf(v, hi16f(h.x), ay);
                az = fmaf(v, lo16f(h.y), az);
                aw = fmaf(v, hi16f(h.y), aw);
            }

            ax += __shfl_xor(ax, 16, 64); ax += __shfl_xor(ax, 32, 64);
            ay += __shfl_xor(ay, 16, 64); ay += __shfl_xor(ay, 32, 64);
            az += __shfl_xor(az, 16, 64); az += __shfl_xor(az, 32, 64);
            aw += __shfl_xor(aw, 16, 64); aw += __shfl_xor(aw, 32, 64);

            float xx = fmaxf(ax, 0.f), xy = fmaxf(ay, 0.f);
            float xz = fmaxf(az, 0.f), xw = fmaxf(aw, 0.f);

            float part = xx*xx + xy*xy + xz*xz + xw*xw;
            float xt_n = fmaxf(sqrtf(group16_reduce_sum(part)), MIN_NORM);
            float txt  = fast_tanh(xt_n);                 // = ||out||
            float s3   = txt * frcp(xt_n);
            if (txt > MAX_N) s3 = MAX_N * frcp(xt_n);     // proj (dormant, kept)
            float ox = xx*s3, oy = xy*s3, oz = xz*s3, ow = xw*s3;

            int gn = b * NPB + n;
            if (g == 0 && gn < NN) {
                float4 o4 = make_float4(ox, oy, oz, ow);
                *(float4*)(out + gn * DD + (lane & 15) * 4) = o4;
            }
        }
        __syncthreads();   // protect cnt_a/srt/raw before next rep
    }
}

extern "C" void kernel_launch(void* const* d_in, const int* in_sizes, int n_in,
                              void* d_out, int out_size, void* d_ws, size_t ws_size,
                              hipStream_t stream) {
    const float* x    = (const float*)d_in[0];
    const float* W    = (const float*)d_in[1];
    const float* ev   = (const float*)d_in[2];
    const int*   rows = (const int*)d_in[3];
    const int*   cols = (const int*)d_in[4];
    float* out = (float*)d_out;

    char* ws = (char*)d_ws;
    __half* hidden = (__half*)ws;                 // 12,800,000 B
    int2*   csr    = (int2*)(ws + 12800000);      // 12,800,000 B
    int*    cnt    = (int*)(ws + 25600000);       //  1,048,576 B (512x512 counts)
    int*    woff   = (int*)(ws + 26648576);       //  1,048,576 B (per-chunk bucket offsets)
    int*    gcount = (int*)(ws + 27697152);       //      2,048 B
                                                  // total ~27.7 MB

    linear_count_kernel<<<NB, 1024, 0, stream>>>(x, W, rows, hidden, cnt);
    offset_kernel<<<NB / 8, 512, 0, stream>>>(cnt, woff, gcount);
    sort_scatter_kernel<<<NB, 1024, 0, stream>>>(rows, cols, ev, cnt, woff, gcount, csr);
    sortgather_kernel<<<NB, 1024, 0, stream>>>(hidden, csr, gcount, out);
}

// Round 3
// 280.737 us; speedup vs baseline: 2.0326x; 2.0326x over previous
//
#include <hip/hip_runtime.h>
#include <hip/hip_fp16.h>

// Hyperbolic GCN layer, c = 1.0
// x [N,D] f32, W [D,D] f32, edge_vals [E] f32, rows [E] i32, cols [E] i32 -> out [N,D] f32
//
// *** ROUND-15: DIAGNOSTIC BUILD #2 ***
// Attribution so far (R2 diag): t_sortgather ~= 30 us of 147. Remaining ~115 us
// unattributed across linear_count / offset / sort_scatter / inter-kernel gaps.
// This build: linear_count body x16 (REP_LC), sort_scatter body x6 (REP_SS),
// sortgather and offset back to baseline. Both inflated kernels are idempotent.
//   Dtotal = 15*t_lc + 5*t_ss ; top-5 rows give the bigger one directly.
//
// Algebraic note (verified vs reference): with sc=1,
//   logmap0(mobius_matvec(W,x)) = (atanh(||x||)/||x||) * (W x)      [atanh∘tanh cancels]
//   relu(logmap0(expmap0(s)))   = relu(s)                           [logmap0∘expmap0 = id]
//
// Forbidden patterns (measured): scattered per-lane LDS float atomics (R3: 557us,
// R15: 538us); serial chained global atomics for range reservation (R8: 86us stall).
#define NN 100000
#define DD 64
#define EE 1600000
#define NB 512          // node buckets == sort chunks
#define NPB 196         // nodes per bucket (NB*NPB = 100352 >= NN)
#define CHUNK 3125      // edges per chunk (CHUNK * NB == EE)
#define CAP 3520        // per-bucket LDS capacity (mean 3125, sigma ~56 -> +7 sigma)
#define REP_LC 16       // DIAGNOSTIC repetition of linear_count body
#define REP_SS 6        // DIAGNOSTIC repetition of sort_scatter body

typedef _Float16 half8 __attribute__((ext_vector_type(8)));
typedef float floatx4 __attribute__((ext_vector_type(4)));

__device__ __forceinline__ float frcp(float x) { return __builtin_amdgcn_rcpf(x); }

__device__ __forceinline__ float fast_tanh(float x) {           // x >= 0 here
    float t = __expf(2.0f * x);
    return (t - 1.0f) * frcp(t + 1.0f);
}
__device__ __forceinline__ float fast_atanh(float x) {
    const float CLIP = 1.0f - 1e-7f;
    x = fminf(fmaxf(x, -CLIP), CLIP);
    return 0.5f * __logf((1.0f + x) * frcp(1.0f - x));
}
__device__ __forceinline__ float group16_reduce_sum(float v) {
    #pragma unroll
    for (int m = 8; m > 0; m >>= 1) v += __shfl_xor(v, m, 16);
    return v;
}
__device__ __forceinline__ float lo16f(unsigned u) {
    return __half2float(__ushort_as_half((unsigned short)(u & 0xFFFFu)));
}
__device__ __forceinline__ float hi16f(unsigned u) {
    return __half2float(__ushort_as_half((unsigned short)(u >> 16)));
}

// ---- Stage 1 (MFMA) + per-chunk bucket counts. DIAGNOSTIC: body x REP_LC ----
__global__ __launch_bounds__(1024) void linear_count_kernel(
    const float* __restrict__ x, const float* __restrict__ W,
    const int* __restrict__ rows,
    __half* __restrict__ hidden, int* __restrict__ cnt) {
    __shared__ _Float16 Wh[64 * 80];   // stride 80 halves keeps b128 aligned
    __shared__ int h[NB];
    const int t = threadIdx.x;

    for (int i = t; i < 64 * 64; i += 1024)
        Wh[(i >> 6) * 80 + (i & 63)] = (_Float16)W[i];

    for (int rep = 0; rep < REP_LC; ++rep) {   // DIAGNOSTIC loop, idempotent
        if (t < NB) h[t] = 0;
        __syncthreads();

        {   // histogram this chunk (LDS atomics on 512 int counters only)
            const int e0 = blockIdx.x * CHUNK;
            for (int i = t; i < CHUNK; i += 1024)
                atomicAdd(&h[(unsigned)rows[e0 + i] / NPB], 1);
        }

        const int lane = t & 63;
        const int wv   = t >> 6;             // waves 0..12 do MFMA (13*16=208 nodes)
        if (wv < 13) {
            const int q    = lane >> 4;
            const int c    = lane & 15;
            const int node = blockIdx.x * NPB + wv * 16 + c;
            const int node_ld = (node < NN) ? node : (NN - 1);

            const float MIN_NORM = 1e-15f;
            const float4* xr = (const float4*)(x + node_ld * 64);
            float4 b0a = xr[q * 2];
            float4 b0b = xr[q * 2 + 1];
            float4 b1a = xr[8 + q * 2];
            float4 b1b = xr[8 + q * 2 + 1];

            float xpart = b0a.x*b0a.x + b0a.y*b0a.y + b0a.z*b0a.z + b0a.w*b0a.w
                        + b0b.x*b0b.x + b0b.y*b0b.y + b0b.z*b0b.z + b0b.w*b0b.w
                        + b1a.x*b1a.x + b1a.y*b1a.y + b1a.z*b1a.z + b1a.w*b1a.w
                        + b1b.x*b1b.x + b1b.y*b1b.y + b1b.z*b1b.z + b1b.w*b1b.w;
            xpart += __shfl_xor(xpart, 16, 64);
            xpart += __shfl_xor(xpart, 32, 64);
            float x_n = fmaxf(sqrtf(xpart), MIN_NORM);

            half8 bf0, bf1;
            bf0[0]=(_Float16)b0a.x; bf0[1]=(_Float16)b0a.y; bf0[2]=(_Float16)b0a.z; bf0[3]=(_Float16)b0a.w;
            bf0[4]=(_Float16)b0b.x; bf0[5]=(_Float16)b0b.y; bf0[6]=(_Float16)b0b.z; bf0[7]=(_Float16)b0b.w;
            bf1[0]=(_Float16)b1a.x; bf1[1]=(_Float16)b1a.y; bf1[2]=(_Float16)b1a.z; bf1[3]=(_Float16)b1a.w;
            bf1[4]=(_Float16)b1b.x; bf1[5]=(_Float16)b1b.y; bf1[6]=(_Float16)b1b.z; bf1[7]=(_Float16)b1b.w;

            floatx4 acc[4];
            #pragma unroll
            for (int tt = 0; tt < 4; ++tt) {
                const half8* a0 = (const half8*)&Wh[(16 * tt + c) * 80 + q * 8];
                const half8* a1 = (const half8*)&Wh[(16 * tt + c) * 80 + 32 + q * 8];
                floatx4 z = {0.f, 0.f, 0.f, 0.f};
                z = __builtin_amdgcn_mfma_f32_16x16x32_f16(a0[0], bf0, z, 0, 0, 0);
                z = __builtin_amdgcn_mfma_f32_16x16x32_f16(a1[0], bf1, z, 0, 0, 0);
                acc[tt] = z;
            }

            float hscale = fast_atanh(x_n) * frcp(x_n);

            if (node < NN) {
                #pragma unroll
                for (int tt = 0; tt < 4; ++tt) {
                    __half2 lo = __floats2half2_rn(acc[tt][0] * hscale, acc[tt][1] * hscale);
                    __half2 hi = __floats2half2_rn(acc[tt][2] * hscale, acc[tt][3] * hscale);
                    uint2 pkt;
                    pkt.x = *(unsigned*)&lo;
                    pkt.y = *(unsigned*)&hi;
                    ((uint2*)hidden)[node * 16 + tt * 4 + q] = pkt;
                }
            }
        }
        __syncthreads();
    }
    if (t < NB) cnt[blockIdx.x * NB + t] = h[t];   // coalesced row write
}

// ---- Per-bucket exclusive scan over chunk counts -> woff + bucket totals ----
__global__ __launch_bounds__(512) void offset_kernel(const int* __restrict__ cnt,
                                                     int* __restrict__ woff,
                                                     int* __restrict__ gcount) {
    const int lane = threadIdx.x & 63;
    const int b    = blockIdx.x * 8 + (threadIdx.x >> 6);   // bucket
    int c[8]; int sum = 0;
    #pragma unroll
    for (int k = 0; k < 8; ++k) { c[k] = cnt[(lane * 8 + k) * NB + b]; sum += c[k]; }
    int pre = sum;
    #pragma unroll
    for (int m = 1; m < 64; m <<= 1) {
        int u = __shfl_up(pre, m, 64);
        if (lane >= m) pre += u;
    }
    int run = pre - sum;
    #pragma unroll
    for (int k = 0; k < 8; ++k) { woff[(lane * 8 + k) * NB + b] = run; run += c[k]; }
    if (lane == 63) gcount[b] = run;   // bucket total
}

// ---- Local counting sort + coalesced scatter. DIAGNOSTIC: body x REP_SS ----
// payload: word0 = rl<<24 | col*128 (byte offset into fp16 hidden rows), word1 = val fp32
__global__ __launch_bounds__(1024, 8) void sort_scatter_kernel(
    const int* __restrict__ rows, const int* __restrict__ cols,
    const float* __restrict__ ev, const int* __restrict__ cnt,
    const int* __restrict__ woff, const int* __restrict__ gcount,
    int2* __restrict__ csr) {
    __shared__ int cur[NB];
    __shared__ int delta[NB];
    __shared__ int2 sorted[CHUNK];
    __shared__ unsigned short bid[CHUNK];
    const int t  = threadIdx.x;
    const int e0 = blockIdx.x * CHUNK;

    for (int rep = 0; rep < REP_SS; ++rep) {   // DIAGNOSTIC loop, idempotent
        __syncthreads();   // protect cur/delta/sorted/bid from prior rep readers
        if (t < 64) {
            const int lane = t;
            // exclusive scan of gcount -> bucket bases (redundant per block, cheap)
            int g[8]; int gsum = 0;
            #pragma unroll
            for (int k = 0; k < 8; ++k) { g[k] = gcount[lane * 8 + k]; gsum += g[k]; }
            int gpre = gsum;
            #pragma unroll
            for (int m = 1; m < 64; m <<= 1) {
                int u = __shfl_up(gpre, m, 64);
                if (lane >= m) gpre += u;
            }
            int grun = gpre - gsum;                    // bbase[lane*8]
            // chunk-local counting-sort offsets
            int c[8]; int sum = 0;
            #pragma unroll
            for (int k = 0; k < 8; ++k) { c[k] = cnt[blockIdx.x * NB + lane * 8 + k]; sum += c[k]; }
            int pre = sum;
            #pragma unroll
            for (int m = 1; m < 64; m <<= 1) {
                int u = __shfl_up(pre, m, 64);
                if (lane >= m) pre += u;
            }
            int run = pre - sum;
            #pragma unroll
            for (int k = 0; k < 8; ++k) {
                int b = lane * 8 + k;
                cur[b]   = run;                                  // LDS scatter cursor
                delta[b] = grun + woff[blockIdx.x * NB + b] - run; // LDS pos -> global
                grun += g[k];
                run  += c[k];
            }
        }
        __syncthreads();
        for (int i = t; i < CHUNK; i += 1024) {
            unsigned r = (unsigned)rows[e0 + i];
            unsigned c = (unsigned)cols[e0 + i];
            float v = ev[e0 + i];
            unsigned b  = r / NPB;
            unsigned rl = r - b * NPB;
            int idx = atomicAdd(&cur[b], 1);
            sorted[idx] = make_int2((int)((rl << 24) | (c << 7)), __float_as_int(v));
            bid[idx] = (unsigned short)b;
        }
        __syncthreads();
        for (int i = t; i < CHUNK; i += 1024) {
            int2 eV = sorted[i];
            csr[delta[bid[i]] + i] = eV;
        }
    }
}

// ---- Fused: stage csr segment into LDS once (histogram fused into the staging
//      read), per-bucket node counting-sort LDS->LDS, quarter-wave register
//      gather, epilogue out = proj(expmap0(relu(support))). (baseline form) ----
__global__ __launch_bounds__(1024, 8) void sortgather_kernel(
    const __half* __restrict__ hidden, const int2* __restrict__ csr,
    const int* __restrict__ gcount, float* __restrict__ out) {
    __shared__ int2 raw[CAP];          // 28,160 B, staged csr segment
    __shared__ int2 srt[CAP];          // 28,160 B, node-sorted descriptors
    __shared__ int cnt_a[NPB];
    __shared__ int start[NPB];
    __shared__ int cur[NPB];
    __shared__ int s_lo, s_cnt;
    const int t  = threadIdx.x;
    const int b  = blockIdx.x;

    if (t < NPB) cnt_a[t] = 0;
    if (t < 64) {
        // exclusive scan of gcount; pick out bbase[b] and gcount[b]
        int g[8]; int gsum = 0;
        #pragma unroll
        for (int k = 0; k < 8; ++k) { g[k] = gcount[t * 8 + k]; gsum += g[k]; }
        int gpre = gsum;
        #pragma unroll
        for (int m = 1; m < 64; m <<= 1) {
            int u = __shfl_up(gpre, m, 64);
            if (t >= m) gpre += u;
        }
        int run = gpre - gsum;                 // bbase[t*8]
        #pragma unroll
        for (int k = 0; k < 8; ++k) {
            int bb = t * 8 + k;
            if (bb == b) { s_lo = run; s_cnt = g[k]; }
            run += g[k];
        }
    }
    __syncthreads();
    const int lo  = s_lo;
    int ecnt = s_cnt;
    if (ecnt > CAP) ecnt = CAP;        // statistically unreachable guard

    for (int i = t; i < ecnt; i += 1024) {       // stage + fused histogram
        int2 e = csr[lo + i];
        raw[i] = e;
        atomicAdd(&cnt_a[((unsigned)e.x) >> 24], 1);
    }
    __syncthreads();
    if (t < 64) {
        const int lane = t;
        int c[4]; int sum = 0;
        #pragma unroll
        for (int k = 0; k < 4; ++k) {
            int bb = lane * 4 + k;
            c[k] = (bb < NPB) ? cnt_a[bb] : 0;
            sum += c[k];
        }
        int pre = sum;
        #pragma unroll
        for (int m = 1; m < 64; m <<= 1) {
            int u = __shfl_up(pre, m, 64);
            if (lane >= m) pre += u;
        }
        int run = pre - sum;
        #pragma unroll
        for (int k = 0; k < 4; ++k) {
            int bb = lane * 4 + k;
            if (bb < NPB) { start[bb] = run; cur[bb] = run; run += c[k]; }
        }
    }
    __syncthreads();
    for (int i = t; i < ecnt; i += 1024) {       // LDS -> LDS counting sort
        int2 e = raw[i];
        int p  = atomicAdd(&cur[((unsigned)e.x) >> 24], 1);
        srt[p] = e;
    }
    __syncthreads();

    const int lane = t & 63;
    const int wv   = t >> 6;               // 0..15
    const int g    = lane >> 4;
    const int l8   = (lane & 15) * 8;
    const char* __restrict__ hidc = (const char*)hidden;
    const float MIN_NORM = 1e-15f;
    const float MAX_N = 1.0f - 1e-5f;

    for (int n = wv; n < NPB; n += 16) {
        int i   = start[n];
        int rhi = i + cnt_a[n];
        float ax = 0.f, ay = 0.f, az = 0.f, aw = 0.f;

        for (; i + 16 <= rhi; i += 16) {         // 4 groups of 4 edges in flight
            int2 dA = srt[i + g];
            int2 dB = srt[i + 4 + g];
            int2 dC = srt[i + 8 + g];
            int2 dD = srt[i + 12 + g];
            unsigned oA = (((unsigned)dA.x) & 0xFFFFFFu) + l8;
            unsigned oB = (((unsigned)dB.x) & 0xFFFFFFu) + l8;
            unsigned oC = (((unsigned)dC.x) & 0xFFFFFFu) + l8;
            unsigned oD = (((unsigned)dD.x) & 0xFFFFFFu) + l8;
            uint2 hA = *(const uint2*)(hidc + oA);
            uint2 hB = *(const uint2*)(hidc + oB);
            uint2 hC = *(const uint2*)(hidc + oC);
            uint2 hD = *(const uint2*)(hidc + oD);
            float vA = __int_as_float(dA.y);
            float vB = __int_as_float(dB.y);
            float vC = __int_as_float(dC.y);
            float vD = __int_as_float(dD.y);
            ax = fmaf(vA, lo16f(hA.x), ax);
            ay = fmaf(vA, hi16f(hA.x), ay);
            az = fmaf(vA, lo16f(hA.y), az);
            aw = fmaf(vA, hi16f(hA.y), aw);
            ax = fmaf(vB, lo16f(hB.x), ax);
            ay = fmaf(vB, hi16f(hB.x), ay);
            az = fmaf(vB, lo16f(hB.y), az);
            aw = fmaf(vB, hi16f(hB.y), aw);
            ax = fmaf(vC, lo16f(hC.x), ax);
            ay = fmaf(vC, hi16f(hC.x), ay);
            az = fmaf(vC, lo16f(hC.y), az);
            aw = fmaf(vC, hi16f(hC.y), aw);
            ax = fmaf(vD, lo16f(hD.x), ax);
            ay = fmaf(vD, hi16f(hD.x), ay);
            az = fmaf(vD, lo16f(hD.y), az);
            aw = fmaf(vD, hi16f(hD.y), aw);
        }
        if (i + 8 <= rhi) {                      // 2 groups of 4 edges
            int2 dA = srt[i + g];
            int2 dB = srt[i + 4 + g];
            unsigned oA = (((unsigned)dA.x) & 0xFFFFFFu) + l8;
            unsigned oB = (((unsigned)dB.x) & 0xFFFFFFu) + l8;
            uint2 hA = *(const uint2*)(hidc + oA);
            uint2 hB = *(const uint2*)(hidc + oB);
            float vA = __int_as_float(dA.y);
            float vB = __int_as_float(dB.y);
            ax = fmaf(vA, lo16f(hA.x), ax);
            ay = fmaf(vA, hi16f(hA.x), ay);
            az = fmaf(vA, lo16f(hA.y), az);
            aw = fmaf(vA, hi16f(hA.y), aw);
            ax = fmaf(vB, lo16f(hB.x), ax);
            ay = fmaf(vB, hi16f(hB.x), ay);
            az = fmaf(vB, lo16f(hB.y), az);
            aw = fmaf(vB, hi16f(hB.y), aw);
            i += 8;
        }
        for (; i < rhi; i += 4) {                // masked 4-edge groups (<=2 iters)
            int idx = i + g;
            int2 d = srt[(idx < rhi) ? idx : (rhi - 1)];
            float v = (idx < rhi) ? __int_as_float(d.y) : 0.0f;
            unsigned o = (((unsigned)d.x) & 0xFFFFFFu) + l8;
            uint2 h = *(const uint2*)(hidc + o);
            ax = fmaf(v, lo16f(h.x), ax);
            ay = fmaf(v, hi16f(h.x), ay);
            az = fmaf(v, lo16f(h.y), az);
            aw = fmaf(v, hi16f(h.y), aw);
        }

        ax += __shfl_xor(ax, 16, 64); ax += __shfl_xor(ax, 32, 64);
        ay += __shfl_xor(ay, 16, 64); ay += __shfl_xor(ay, 32, 64);
        az += __shfl_xor(az, 16, 64); az += __shfl_xor(az, 32, 64);
        aw += __shfl_xor(aw, 16, 64); aw += __shfl_xor(aw, 32, 64);

        float xx = fmaxf(ax, 0.f), xy = fmaxf(ay, 0.f);
        float xz = fmaxf(az, 0.f), xw = fmaxf(aw, 0.f);

        float part = xx*xx + xy*xy + xz*xz + xw*xw;
        float xt_n = fmaxf(sqrtf(group16_reduce_sum(part)), MIN_NORM);
        float txt  = fast_tanh(xt_n);                 // = ||out||
        float s3   = txt * frcp(xt_n);
        if (txt > MAX_N) s3 = MAX_N * frcp(xt_n);     // proj (dormant, kept)
        float ox = xx*s3, oy = xy*s3, oz = xz*s3, ow = xw*s3;

        int gn = b * NPB + n;
        if (g == 0 && gn < NN) {
            float4 o4 = make_float4(ox, oy, oz, ow);
            *(float4*)(out + gn * DD + (lane & 15) * 4) = o4;
        }
    }
}

extern "C" void kernel_launch(void* const* d_in, const int* in_sizes, int n_in,
                              void* d_out, int out_size, void* d_ws, size_t ws_size,
                              hipStream_t stream) {
    const float* x    = (const float*)d_in[0];
    const float* W    = (const float*)d_in[1];
    const float* ev   = (const float*)d_in[2];
    const int*   rows = (const int*)d_in[3];
    const int*   cols = (const int*)d_in[4];
    float* out = (float*)d_out;

    char* ws = (char*)d_ws;
    __half* hidden = (__half*)ws;                 // 12,800,000 B
    int2*   csr    = (int2*)(ws + 12800000);      // 12,800,000 B
    int*    cnt    = (int*)(ws + 25600000);       //  1,048,576 B (512x512 counts)
    int*    woff   = (int*)(ws + 26648576);       //  1,048,576 B (per-chunk bucket offsets)
    int*    gcount = (int*)(ws + 27697152);       //      2,048 B
                                                  // total ~27.7 MB

    linear_count_kernel<<<NB, 1024, 0, stream>>>(x, W, rows, hidden, cnt);
    offset_kernel<<<NB / 8, 512, 0, stream>>>(cnt, woff, gcount);
    sort_scatter_kernel<<<NB, 1024, 0, stream>>>(rows, cols, ev, cnt, woff, gcount, csr);
    sortgather_kernel<<<NB, 1024, 0, stream>>>(hidden, csr, gcount, out);
}

// Round 4
// 148.597 us; speedup vs baseline: 3.8402x; 1.8892x over previous
//
#include <hip/hip_runtime.h>
#include <hip/hip_fp16.h>

// Hyperbolic GCN layer, c = 1.0
// x [N,D] f32, W [D,D] f32, edge_vals [E] f32, rows [E] i32, cols [E] i32 -> out [N,D] f32
//
// Algebraic note (verified vs reference): with sc=1,
//   logmap0(mobius_matvec(W,x)) = (atanh(||x||)/||x||) * (W x)      [atanh∘tanh cancels]
//   relu(logmap0(expmap0(s)))   = relu(s)                           [logmap0∘expmap0 = id]
//
// Attribution (R2/R3 diagnostics, measured): t_lc 7.5us (at roofline), offset ~1.5us,
// t_ss 4.3us (at roofline), t_sg 28.2us (VALUBusy 74%, occ 85%); remaining ~105us of
// dur_us is harness reset (256MiB fill + memsets), not addressable. Only sortgather
// is meaningfully above its floor -> this round cuts its gather VALU:
//   - v_fma_mix_f32 (f16 src, f32 acc) via inline asm: 12 -> 4 VALU per edge-quarter
//   - edge-pair packing + ds_read_b128 descriptor reads (even-aligned node starts
//     via padded prefix sums; pad slots never read)
// Forbidden patterns (measured): scattered per-lane LDS float atomics (R3: 557us,
// R15: 538us); serial chained global atomics for range reservation (R8: 86us stall).
#define NN 100000
#define DD 64
#define EE 1600000
#define NB 512          // node buckets == sort chunks
#define NPB 196         // nodes per bucket (NB*NPB = 100352 >= NN)
#define CHUNK 3125      // edges per chunk (CHUNK * NB == EE)
#define CAP 3520        // per-bucket LDS capacity (mean 3125, sigma ~56 -> +7 sigma)
#define CAP2 3720       // srt capacity with per-node even-padding (CAP + NPB, rounded)

typedef _Float16 half8 __attribute__((ext_vector_type(8)));
typedef float floatx4 __attribute__((ext_vector_type(4)));

__device__ __forceinline__ float frcp(float x) { return __builtin_amdgcn_rcpf(x); }

__device__ __forceinline__ float fast_tanh(float x) {           // x >= 0 here
    float t = __expf(2.0f * x);
    return (t - 1.0f) * frcp(t + 1.0f);
}
__device__ __forceinline__ float fast_atanh(float x) {
    const float CLIP = 1.0f - 1e-7f;
    x = fminf(fmaxf(x, -CLIP), CLIP);
    return 0.5f * __logf((1.0f + x) * frcp(1.0f - x));
}
__device__ __forceinline__ float group16_reduce_sum(float v) {
    #pragma unroll
    for (int m = 8; m > 0; m >>= 1) v += __shfl_xor(v, m, 16);
    return v;
}
// acc += v * f16(lo/hi 16 bits of h); f32 accumulate. One VALU op, numerics
// identical to cvt+fmaf. op_sel_hi[1]=1 marks S1 as f16 (others f32).
__device__ __forceinline__ void fmix_lo(float& a, float v, unsigned h) {
    asm("v_fma_mix_f32 %0, %1, %2, %0 op_sel:[0,0,0] op_sel_hi:[0,1,0]"
        : "+v"(a) : "v"(v), "v"(h));
}
__device__ __forceinline__ void fmix_hi(float& a, float v, unsigned h) {
    asm("v_fma_mix_f32 %0, %1, %2, %0 op_sel:[0,1,0] op_sel_hi:[0,1,0]"
        : "+v"(a) : "v"(v), "v"(h));
}

// ---- Stage 1 (MFMA) + per-chunk bucket counts ----
__global__ __launch_bounds__(1024) void linear_count_kernel(
    const float* __restrict__ x, const float* __restrict__ W,
    const int* __restrict__ rows,
    __half* __restrict__ hidden, int* __restrict__ cnt) {
    __shared__ _Float16 Wh[64 * 80];   // stride 80 halves keeps b128 aligned
    __shared__ int h[NB];
    const int t = threadIdx.x;

    if (t < NB) h[t] = 0;
    for (int i = t; i < 64 * 64; i += 1024)
        Wh[(i >> 6) * 80 + (i & 63)] = (_Float16)W[i];
    __syncthreads();

    {   // histogram this chunk (LDS atomics on 512 int counters only)
        const int e0 = blockIdx.x * CHUNK;
        for (int i = t; i < CHUNK; i += 1024)
            atomicAdd(&h[(unsigned)rows[e0 + i] / NPB], 1);
    }

    const int lane = t & 63;
    const int wv   = t >> 6;             // waves 0..12 do MFMA (13*16=208 nodes)
    if (wv < 13) {
        const int q    = lane >> 4;
        const int c    = lane & 15;
        const int node = blockIdx.x * NPB + wv * 16 + c;
        const int node_ld = (node < NN) ? node : (NN - 1);

        const float MIN_NORM = 1e-15f;
        const float4* xr = (const float4*)(x + node_ld * 64);
        float4 b0a = xr[q * 2];
        float4 b0b = xr[q * 2 + 1];
        float4 b1a = xr[8 + q * 2];
        float4 b1b = xr[8 + q * 2 + 1];

        float xpart = b0a.x*b0a.x + b0a.y*b0a.y + b0a.z*b0a.z + b0a.w*b0a.w
                    + b0b.x*b0b.x + b0b.y*b0b.y + b0b.z*b0b.z + b0b.w*b0b.w
                    + b1a.x*b1a.x + b1a.y*b1a.y + b1a.z*b1a.z + b1a.w*b1a.w
                    + b1b.x*b1b.x + b1b.y*b1b.y + b1b.z*b1b.z + b1b.w*b1b.w;
        xpart += __shfl_xor(xpart, 16, 64);
        xpart += __shfl_xor(xpart, 32, 64);
        float x_n = fmaxf(sqrtf(xpart), MIN_NORM);

        half8 bf0, bf1;
        bf0[0]=(_Float16)b0a.x; bf0[1]=(_Float16)b0a.y; bf0[2]=(_Float16)b0a.z; bf0[3]=(_Float16)b0a.w;
        bf0[4]=(_Float16)b0b.x; bf0[5]=(_Float16)b0b.y; bf0[6]=(_Float16)b0b.z; bf0[7]=(_Float16)b0b.w;
        bf1[0]=(_Float16)b1a.x; bf1[1]=(_Float16)b1a.y; bf1[2]=(_Float16)b1a.z; bf1[3]=(_Float16)b1a.w;
        bf1[4]=(_Float16)b1b.x; bf1[5]=(_Float16)b1b.y; bf1[6]=(_Float16)b1b.z; bf1[7]=(_Float16)b1b.w;

        floatx4 acc[4];
        #pragma unroll
        for (int tt = 0; tt < 4; ++tt) {
            const half8* a0 = (const half8*)&Wh[(16 * tt + c) * 80 + q * 8];
            const half8* a1 = (const half8*)&Wh[(16 * tt + c) * 80 + 32 + q * 8];
            floatx4 z = {0.f, 0.f, 0.f, 0.f};
            z = __builtin_amdgcn_mfma_f32_16x16x32_f16(a0[0], bf0, z, 0, 0, 0);
            z = __builtin_amdgcn_mfma_f32_16x16x32_f16(a1[0], bf1, z, 0, 0, 0);
            acc[tt] = z;
        }

        float hscale = fast_atanh(x_n) * frcp(x_n);

        if (node < NN) {
            #pragma unroll
            for (int tt = 0; tt < 4; ++tt) {
                __half2 lo = __floats2half2_rn(acc[tt][0] * hscale, acc[tt][1] * hscale);
                __half2 hi = __floats2half2_rn(acc[tt][2] * hscale, acc[tt][3] * hscale);
                uint2 pkt;
                pkt.x = *(unsigned*)&lo;
                pkt.y = *(unsigned*)&hi;
                ((uint2*)hidden)[node * 16 + tt * 4 + q] = pkt;
            }
        }
    }
    __syncthreads();
    if (t < NB) cnt[blockIdx.x * NB + t] = h[t];   // coalesced row write
}

// ---- Per-bucket exclusive scan over chunk counts -> woff + bucket totals ----
__global__ __launch_bounds__(512) void offset_kernel(const int* __restrict__ cnt,
                                                     int* __restrict__ woff,
                                                     int* __restrict__ gcount) {
    const int lane = threadIdx.x & 63;
    const int b    = blockIdx.x * 8 + (threadIdx.x >> 6);   // bucket
    int c[8]; int sum = 0;
    #pragma unroll
    for (int k = 0; k < 8; ++k) { c[k] = cnt[(lane * 8 + k) * NB + b]; sum += c[k]; }
    int pre = sum;
    #pragma unroll
    for (int m = 1; m < 64; m <<= 1) {
        int u = __shfl_up(pre, m, 64);
        if (lane >= m) pre += u;
    }
    int run = pre - sum;
    #pragma unroll
    for (int k = 0; k < 8; ++k) { woff[(lane * 8 + k) * NB + b] = run; run += c[k]; }
    if (lane == 63) gcount[b] = run;   // bucket total
}

// ---- Local counting sort + coalesced scatter. Counts precomputed; deterministic
//      offsets, no global atomics. Bucket-base scan recomputed per block. ----
// payload: word0 = rl<<24 | col*128 (byte offset into fp16 hidden rows), word1 = val fp32
__global__ __launch_bounds__(1024, 8) void sort_scatter_kernel(
    const int* __restrict__ rows, const int* __restrict__ cols,
    const float* __restrict__ ev, const int* __restrict__ cnt,
    const int* __restrict__ woff, const int* __restrict__ gcount,
    int2* __restrict__ csr) {
    __shared__ int cur[NB];
    __shared__ int delta[NB];
    __shared__ int2 sorted[CHUNK];
    __shared__ unsigned short bid[CHUNK];
    const int t  = threadIdx.x;
    const int e0 = blockIdx.x * CHUNK;

    if (t < 64) {
        const int lane = t;
        // exclusive scan of gcount -> bucket bases (redundant per block, cheap)
        int g[8]; int gsum = 0;
        #pragma unroll
        for (int k = 0; k < 8; ++k) { g[k] = gcount[lane * 8 + k]; gsum += g[k]; }
        int gpre = gsum;
        #pragma unroll
        for (int m = 1; m < 64; m <<= 1) {
            int u = __shfl_up(gpre, m, 64);
            if (lane >= m) gpre += u;
        }
        int grun = gpre - gsum;                    // bbase[lane*8]
        // chunk-local counting-sort offsets
        int c[8]; int sum = 0;
        #pragma unroll
        for (int k = 0; k < 8; ++k) { c[k] = cnt[blockIdx.x * NB + lane * 8 + k]; sum += c[k]; }
        int pre = sum;
        #pragma unroll
        for (int m = 1; m < 64; m <<= 1) {
            int u = __shfl_up(pre, m, 64);
            if (lane >= m) pre += u;
        }
        int run = pre - sum;
        #pragma unroll
        for (int k = 0; k < 8; ++k) {
            int b = lane * 8 + k;
            cur[b]   = run;                                  // LDS scatter cursor
            delta[b] = grun + woff[blockIdx.x * NB + b] - run; // LDS pos -> global
            grun += g[k];
            run  += c[k];
        }
    }
    __syncthreads();
    for (int i = t; i < CHUNK; i += 1024) {
        unsigned r = (unsigned)rows[e0 + i];
        unsigned c = (unsigned)cols[e0 + i];
        float v = ev[e0 + i];
        unsigned b  = r / NPB;
        unsigned rl = r - b * NPB;
        int idx = atomicAdd(&cur[b], 1);
        sorted[idx] = make_int2((int)((rl << 24) | (c << 7)), __float_as_int(v));
        bid[idx] = (unsigned short)b;
    }
    __syncthreads();
    for (int i = t; i < CHUNK; i += 1024) {
        int2 eV = sorted[i];
        csr[delta[bid[i]] + i] = eV;
    }
}

// ---- Fused: stage csr segment into LDS once (histogram fused into the staging
//      read), per-bucket node counting-sort LDS->LDS with EVEN-ALIGNED node
//      starts, edge-pair b128 descriptor reads, v_fma_mix gather, epilogue
//      out = proj(expmap0(relu(support))). ----
__global__ __launch_bounds__(1024, 8) void sortgather_kernel(
    const __half* __restrict__ hidden, const int2* __restrict__ csr,
    const int* __restrict__ gcount, float* __restrict__ out) {
    __shared__ int2 raw[CAP];                      // 28,160 B, staged csr segment
    __shared__ __align__(16) int2 srt[CAP2];       // 29,760 B, node-sorted (padded)
    __shared__ int cnt_a[NPB];
    __shared__ int start[NPB];
    __shared__ int cur[NPB];
    __shared__ int s_lo, s_cnt;
    const int t  = threadIdx.x;
    const int b  = blockIdx.x;

    if (t < NPB) cnt_a[t] = 0;
    if (t < 64) {
        // exclusive scan of gcount; pick out bbase[b] and gcount[b]
        int g[8]; int gsum = 0;
        #pragma unroll
        for (int k = 0; k < 8; ++k) { g[k] = gcount[t * 8 + k]; gsum += g[k]; }
        int gpre = gsum;
        #pragma unroll
        for (int m = 1; m < 64; m <<= 1) {
            int u = __shfl_up(gpre, m, 64);
            if (t >= m) gpre += u;
        }
        int run = gpre - gsum;                 // bbase[t*8]
        #pragma unroll
        for (int k = 0; k < 8; ++k) {
            int bb = t * 8 + k;
            if (bb == b) { s_lo = run; s_cnt = g[k]; }
            run += g[k];
        }
    }
    __syncthreads();
    const int lo  = s_lo;
    int ecnt = s_cnt;
    if (ecnt > CAP) ecnt = CAP;        // statistically unreachable guard

    for (int i = t; i < ecnt; i += 1024) {       // stage + fused histogram
        int2 e = csr[lo + i];
        raw[i] = e;
        atomicAdd(&cnt_a[((unsigned)e.x) >> 24], 1);
    }
    __syncthreads();
    if (t < 64) {
        const int lane = t;
        int c[4]; int sum = 0;
        #pragma unroll
        for (int k = 0; k < 4; ++k) {
            int bb = lane * 4 + k;
            c[k] = (bb < NPB) ? cnt_a[bb] : 0;
            sum += (c[k] + 1) & ~1;            // even-padded sizes
        }
        int pre = sum;
        #pragma unroll
        for (int m = 1; m < 64; m <<= 1) {
            int u = __shfl_up(pre, m, 64);
            if (lane >= m) pre += u;
        }
        int run = pre - sum;                   // exclusive scan of padded sizes
        #pragma unroll
        for (int k = 0; k < 4; ++k) {
            int bb = lane * 4 + k;
            if (bb < NPB) {
                start[bb] = run;               // 2-edge (16 B) aligned
                cur[bb]   = run;
                run += (c[k] + 1) & ~1;
            }
        }
    }
    __syncthreads();
    for (int i = t; i < ecnt; i += 1024) {       // LDS -> LDS counting sort
        int2 e = raw[i];
        int p  = atomicAdd(&cur[((unsigned)e.x) >> 24], 1);
        srt[p] = e;                              // pad slots stay stale, never read
    }
    __syncthreads();

    const int lane = t & 63;
    const int wv   = t >> 6;               // 0..15
    const int g    = lane >> 4;
    const int l8   = (lane & 15) * 8;
    const char* __restrict__ hidc = (const char*)hidden;
    const float MIN_NORM = 1e-15f;
    const float MAX_N = 1.0f - 1e-5f;

    for (int n = wv; n < NPB; n += 16) {
        int i   = start[n];                  // even
        int rhi = i + cnt_a[n];
        float ax = 0.f, ay = 0.f, az = 0.f, aw = 0.f;

        for (; i + 16 <= rhi; i += 16) {     // lane's quarter handles edges 2g,2g+1,8+2g,8+2g+1
            const int4* sp = (const int4*)__builtin_assume_aligned(srt + i, 16);
            int4 dA = sp[g];
            int4 dB = sp[g + 4];
            unsigned oA0 = (((unsigned)dA.x) & 0xFFFFFFu) + l8;
            unsigned oA1 = (((unsigned)dA.z) & 0xFFFFFFu) + l8;
            unsigned oB0 = (((unsigned)dB.x) & 0xFFFFFFu) + l8;
            unsigned oB1 = (((unsigned)dB.z) & 0xFFFFFFu) + l8;
            uint2 hA0 = *(const uint2*)(hidc + oA0);
            uint2 hA1 = *(const uint2*)(hidc + oA1);
            uint2 hB0 = *(const uint2*)(hidc + oB0);
            uint2 hB1 = *(const uint2*)(hidc + oB1);
            float vA0 = __int_as_float(dA.y);
            float vA1 = __int_as_float(dA.w);
            float vB0 = __int_as_float(dB.y);
            float vB1 = __int_as_float(dB.w);
            fmix_lo(ax, vA0, hA0.x); fmix_hi(ay, vA0, hA0.x);
            fmix_lo(az, vA0, hA0.y); fmix_hi(aw, vA0, hA0.y);
            fmix_lo(ax, vA1, hA1.x); fmix_hi(ay, vA1, hA1.x);
            fmix_lo(az, vA1, hA1.y); fmix_hi(aw, vA1, hA1.y);
            fmix_lo(ax, vB0, hB0.x); fmix_hi(ay, vB0, hB0.x);
            fmix_lo(az, vB0, hB0.y); fmix_hi(aw, vB0, hB0.y);
            fmix_lo(ax, vB1, hB1.x); fmix_hi(ay, vB1, hB1.x);
            fmix_lo(az, vB1, hB1.y); fmix_hi(aw, vB1, hB1.y);
        }
        if (i + 8 <= rhi) {                  // one pair per lane
            const int4* sp = (const int4*)__builtin_assume_aligned(srt + i, 16);
            int4 dA = sp[g];
            unsigned oA0 = (((unsigned)dA.x) & 0xFFFFFFu) + l8;
            unsigned oA1 = (((unsigned)dA.z) & 0xFFFFFFu) + l8;
            uint2 hA0 = *(const uint2*)(hidc + oA0);
            uint2 hA1 = *(const uint2*)(hidc + oA1);
            float vA0 = __int_as_float(dA.y);
            float vA1 = __int_as_float(dA.w);
            fmix_lo(ax, vA0, hA0.x); fmix_hi(ay, vA0, hA0.x);
            fmix_lo(az, vA0, hA0.y); fmix_hi(aw, vA0, hA0.y);
            fmix_lo(ax, vA1, hA1.x); fmix_hi(ay, vA1, hA1.x);
            fmix_lo(az, vA1, hA1.y); fmix_hi(aw, vA1, hA1.y);
            i += 8;
        }
        for (; i < rhi; i += 4) {            // masked 4-edge groups (<=2 iters)
            int idx = i + g;
            int2 d = srt[(idx < rhi) ? idx : (rhi - 1)];
            float v = (idx < rhi) ? __int_as_float(d.y) : 0.0f;
            unsigned o = (((unsigned)d.x) & 0xFFFFFFu) + l8;
            uint2 h = *(const uint2*)(hidc + o);
            fmix_lo(ax, v, h.x); fmix_hi(ay, v, h.x);
            fmix_lo(az, v, h.y); fmix_hi(aw, v, h.y);
        }

        ax += __shfl_xor(ax, 16, 64); ax += __shfl_xor(ax, 32, 64);
        ay += __shfl_xor(ay, 16, 64); ay += __shfl_xor(ay, 32, 64);
        az += __shfl_xor(az, 16, 64); az += __shfl_xor(az, 32, 64);
        aw += __shfl_xor(aw, 16, 64); aw += __shfl_xor(aw, 32, 64);

        float xx = fmaxf(ax, 0.f), xy = fmaxf(ay, 0.f);
        float xz = fmaxf(az, 0.f), xw = fmaxf(aw, 0.f);

        float part = xx*xx + xy*xy + xz*xz + xw*xw;
        float xt_n = fmaxf(sqrtf(group16_reduce_sum(part)), MIN_NORM);
        float txt  = fast_tanh(xt_n);                 // = ||out||
        float s3   = txt * frcp(xt_n);
        if (txt > MAX_N) s3 = MAX_N * frcp(xt_n);     // proj (dormant, kept)
        float ox = xx*s3, oy = xy*s3, oz = xz*s3, ow = xw*s3;

        int gn = b * NPB + n;
        if (g == 0 && gn < NN) {
            float4 o4 = make_float4(ox, oy, oz, ow);
            *(float4*)(out + gn * DD + (lane & 15) * 4) = o4;
        }
    }
}

extern "C" void kernel_launch(void* const* d_in, const int* in_sizes, int n_in,
                              void* d_out, int out_size, void* d_ws, size_t ws_size,
                              hipStream_t stream) {
    const float* x    = (const float*)d_in[0];
    const float* W    = (const float*)d_in[1];
    const float* ev   = (const float*)d_in[2];
    const int*   rows = (const int*)d_in[3];
    const int*   cols = (const int*)d_in[4];
    float* out = (float*)d_out;

    char* ws = (char*)d_ws;
    __half* hidden = (__half*)ws;                 // 12,800,000 B
    int2*   csr    = (int2*)(ws + 12800000);      // 12,800,000 B
    int*    cnt    = (int*)(ws + 25600000);       //  1,048,576 B (512x512 counts)
    int*    woff   = (int*)(ws + 26648576);       //  1,048,576 B (per-chunk bucket offsets)
    int*    gcount = (int*)(ws + 27697152);       //      2,048 B
                                                  // total ~27.7 MB

    linear_count_kernel<<<NB, 1024, 0, stream>>>(x, W, rows, hidden, cnt);
    offset_kernel<<<NB / 8, 512, 0, stream>>>(cnt, woff, gcount);
    sort_scatter_kernel<<<NB, 1024, 0, stream>>>(rows, cols, ev, cnt, woff, gcount, csr);
    sortgather_kernel<<<NB, 1024, 0, stream>>>(hidden, csr, gcount, out);
}

// Round 5
// 146.894 us; speedup vs baseline: 3.8847x; 1.0116x over previous
//
#include <hip/hip_runtime.h>
#include <hip/hip_fp16.h>

// Hyperbolic GCN layer, c = 1.0
// x [N,D] f32, W [D,D] f32, edge_vals [E] f32, rows [E] i32, cols [E] i32 -> out [N,D] f32
//
// Algebraic note (verified vs reference): with sc=1,
//   logmap0(mobius_matvec(W,x)) = (atanh(||x||)/||x||) * (W x)      [atanh∘tanh cancels]
//   relu(logmap0(expmap0(s)))   = relu(s)                           [logmap0∘expmap0 = id]
//
// FINAL CONFIGURATION (round-17 = round-13 form, best measured 147.09 us).
// Attribution (R2/R3 rep-inflation diagnostics, measured on MI355X):
//   linear_count 7.5us (== 47MB/6.3TB/s roofline)   offset ~1.5us (floor)
//   sort_scatter 4.3us (== 32MB roofline)            sortgather ~28us (floor ~21us)
//   harness reset (256MiB fillBufferAligned + memsets): ~105us of dur_us, fixed.
// Null results (measured): removing scan_kernel launch + csr re-read + 16-deep ILP
// (R1: 147.4->147.1, noise); v_fma_mix gather + b128 edge-pairing (R4: 148.6,
// noise-worse -> reverted). sortgather is jointly VALU-issue (74% busy) and
// L2/L3-gather bound; no single >=2us lever remains.
// Forbidden patterns (measured): scattered per-lane LDS float atomics (R3: 557us,
// R15: 538us); serial chained global atomics for range reservation (R8: 86us stall).
#define NN 100000
#define DD 64
#define EE 1600000
#define NB 512          // node buckets == sort chunks
#define NPB 196         // nodes per bucket (NB*NPB = 100352 >= NN)
#define CHUNK 3125      // edges per chunk (CHUNK * NB == EE)
#define CAP 3520        // per-bucket LDS capacity (mean 3125, sigma ~56 -> +7 sigma)

typedef _Float16 half8 __attribute__((ext_vector_type(8)));
typedef float floatx4 __attribute__((ext_vector_type(4)));

__device__ __forceinline__ float frcp(float x) { return __builtin_amdgcn_rcpf(x); }

__device__ __forceinline__ float fast_tanh(float x) {           // x >= 0 here
    float t = __expf(2.0f * x);
    return (t - 1.0f) * frcp(t + 1.0f);
}
__device__ __forceinline__ float fast_atanh(float x) {
    const float CLIP = 1.0f - 1e-7f;
    x = fminf(fmaxf(x, -CLIP), CLIP);
    return 0.5f * __logf((1.0f + x) * frcp(1.0f - x));
}
__device__ __forceinline__ float group16_reduce_sum(float v) {
    #pragma unroll
    for (int m = 8; m > 0; m >>= 1) v += __shfl_xor(v, m, 16);
    return v;
}
__device__ __forceinline__ float lo16f(unsigned u) {
    return __half2float(__ushort_as_half((unsigned short)(u & 0xFFFFu)));
}
__device__ __forceinline__ float hi16f(unsigned u) {
    return __half2float(__ushort_as_half((unsigned short)(u >> 16)));
}

// ---- Stage 1 (MFMA) + per-chunk bucket counts ----
__global__ __launch_bounds__(1024) void linear_count_kernel(
    const float* __restrict__ x, const float* __restrict__ W,
    const int* __restrict__ rows,
    __half* __restrict__ hidden, int* __restrict__ cnt) {
    __shared__ _Float16 Wh[64 * 80];   // stride 80 halves keeps b128 aligned
    __shared__ int h[NB];
    const int t = threadIdx.x;

    if (t < NB) h[t] = 0;
    for (int i = t; i < 64 * 64; i += 1024)
        Wh[(i >> 6) * 80 + (i & 63)] = (_Float16)W[i];
    __syncthreads();

    {   // histogram this chunk (LDS atomics on 512 int counters only)
        const int e0 = blockIdx.x * CHUNK;
        for (int i = t; i < CHUNK; i += 1024)
            atomicAdd(&h[(unsigned)rows[e0 + i] / NPB], 1);
    }

    const int lane = t & 63;
    const int wv   = t >> 6;             // waves 0..12 do MFMA (13*16=208 nodes)
    if (wv < 13) {
        const int q    = lane >> 4;
        const int c    = lane & 15;
        const int node = blockIdx.x * NPB + wv * 16 + c;
        const int node_ld = (node < NN) ? node : (NN - 1);

        const float MIN_NORM = 1e-15f;
        const float4* xr = (const float4*)(x + node_ld * 64);
        float4 b0a = xr[q * 2];
        float4 b0b = xr[q * 2 + 1];
        float4 b1a = xr[8 + q * 2];
        float4 b1b = xr[8 + q * 2 + 1];

        float xpart = b0a.x*b0a.x + b0a.y*b0a.y + b0a.z*b0a.z + b0a.w*b0a.w
                    + b0b.x*b0b.x + b0b.y*b0b.y + b0b.z*b0b.z + b0b.w*b0b.w
                    + b1a.x*b1a.x + b1a.y*b1a.y + b1a.z*b1a.z + b1a.w*b1a.w
                    + b1b.x*b1b.x + b1b.y*b1b.y + b1b.z*b1b.z + b1b.w*b1b.w;
        xpart += __shfl_xor(xpart, 16, 64);
        xpart += __shfl_xor(xpart, 32, 64);
        float x_n = fmaxf(sqrtf(xpart), MIN_NORM);

        half8 bf0, bf1;
        bf0[0]=(_Float16)b0a.x; bf0[1]=(_Float16)b0a.y; bf0[2]=(_Float16)b0a.z; bf0[3]=(_Float16)b0a.w;
        bf0[4]=(_Float16)b0b.x; bf0[5]=(_Float16)b0b.y; bf0[6]=(_Float16)b0b.z; bf0[7]=(_Float16)b0b.w;
        bf1[0]=(_Float16)b1a.x; bf1[1]=(_Float16)b1a.y; bf1[2]=(_Float16)b1a.z; bf1[3]=(_Float16)b1a.w;
        bf1[4]=(_Float16)b1b.x; bf1[5]=(_Float16)b1b.y; bf1[6]=(_Float16)b1b.z; bf1[7]=(_Float16)b1b.w;

        floatx4 acc[4];
        #pragma unroll
        for (int tt = 0; tt < 4; ++tt) {
            const half8* a0 = (const half8*)&Wh[(16 * tt + c) * 80 + q * 8];
            const half8* a1 = (const half8*)&Wh[(16 * tt + c) * 80 + 32 + q * 8];
            floatx4 z = {0.f, 0.f, 0.f, 0.f};
            z = __builtin_amdgcn_mfma_f32_16x16x32_f16(a0[0], bf0, z, 0, 0, 0);
            z = __builtin_amdgcn_mfma_f32_16x16x32_f16(a1[0], bf1, z, 0, 0, 0);
            acc[tt] = z;
        }

        float hscale = fast_atanh(x_n) * frcp(x_n);

        if (node < NN) {
            #pragma unroll
            for (int tt = 0; tt < 4; ++tt) {
                __half2 lo = __floats2half2_rn(acc[tt][0] * hscale, acc[tt][1] * hscale);
                __half2 hi = __floats2half2_rn(acc[tt][2] * hscale, acc[tt][3] * hscale);
                uint2 pkt;
                pkt.x = *(unsigned*)&lo;
                pkt.y = *(unsigned*)&hi;
                ((uint2*)hidden)[node * 16 + tt * 4 + q] = pkt;
            }
        }
    }
    __syncthreads();
    if (t < NB) cnt[blockIdx.x * NB + t] = h[t];   // coalesced row write
}

// ---- Per-bucket exclusive scan over chunk counts -> woff + bucket totals ----
__global__ __launch_bounds__(512) void offset_kernel(const int* __restrict__ cnt,
                                                     int* __restrict__ woff,
                                                     int* __restrict__ gcount) {
    const int lane = threadIdx.x & 63;
    const int b    = blockIdx.x * 8 + (threadIdx.x >> 6);   // bucket
    int c[8]; int sum = 0;
    #pragma unroll
    for (int k = 0; k < 8; ++k) { c[k] = cnt[(lane * 8 + k) * NB + b]; sum += c[k]; }
    int pre = sum;
    #pragma unroll
    for (int m = 1; m < 64; m <<= 1) {
        int u = __shfl_up(pre, m, 64);
        if (lane >= m) pre += u;
    }
    int run = pre - sum;
    #pragma unroll
    for (int k = 0; k < 8; ++k) { woff[(lane * 8 + k) * NB + b] = run; run += c[k]; }
    if (lane == 63) gcount[b] = run;   // bucket total
}

// ---- Local counting sort + coalesced scatter. Counts precomputed; deterministic
//      offsets, no global atomics. Bucket-base scan recomputed per block. ----
// payload: word0 = rl<<24 | col*128 (byte offset into fp16 hidden rows), word1 = val fp32
__global__ __launch_bounds__(1024, 8) void sort_scatter_kernel(
    const int* __restrict__ rows, const int* __restrict__ cols,
    const float* __restrict__ ev, const int* __restrict__ cnt,
    const int* __restrict__ woff, const int* __restrict__ gcount,
    int2* __restrict__ csr) {
    __shared__ int cur[NB];
    __shared__ int delta[NB];
    __shared__ int2 sorted[CHUNK];
    __shared__ unsigned short bid[CHUNK];
    const int t  = threadIdx.x;
    const int e0 = blockIdx.x * CHUNK;

    if (t < 64) {
        const int lane = t;
        // exclusive scan of gcount -> bucket bases (redundant per block, cheap)
        int g[8]; int gsum = 0;
        #pragma unroll
        for (int k = 0; k < 8; ++k) { g[k] = gcount[lane * 8 + k]; gsum += g[k]; }
        int gpre = gsum;
        #pragma unroll
        for (int m = 1; m < 64; m <<= 1) {
            int u = __shfl_up(gpre, m, 64);
            if (lane >= m) gpre += u;
        }
        int grun = gpre - gsum;                    // bbase[lane*8]
        // chunk-local counting-sort offsets
        int c[8]; int sum = 0;
        #pragma unroll
        for (int k = 0; k < 8; ++k) { c[k] = cnt[blockIdx.x * NB + lane * 8 + k]; sum += c[k]; }
        int pre = sum;
        #pragma unroll
        for (int m = 1; m < 64; m <<= 1) {
            int u = __shfl_up(pre, m, 64);
            if (lane >= m) pre += u;
        }
        int run = pre - sum;
        #pragma unroll
        for (int k = 0; k < 8; ++k) {
            int b = lane * 8 + k;
            cur[b]   = run;                                  // LDS scatter cursor
            delta[b] = grun + woff[blockIdx.x * NB + b] - run; // LDS pos -> global
            grun += g[k];
            run  += c[k];
        }
    }
    __syncthreads();
    for (int i = t; i < CHUNK; i += 1024) {
        unsigned r = (unsigned)rows[e0 + i];
        unsigned c = (unsigned)cols[e0 + i];
        float v = ev[e0 + i];
        unsigned b  = r / NPB;
        unsigned rl = r - b * NPB;
        int idx = atomicAdd(&cur[b], 1);
        sorted[idx] = make_int2((int)((rl << 24) | (c << 7)), __float_as_int(v));
        bid[idx] = (unsigned short)b;
    }
    __syncthreads();
    for (int i = t; i < CHUNK; i += 1024) {
        int2 eV = sorted[i];
        csr[delta[bid[i]] + i] = eV;
    }
}

// ---- Fused: stage csr segment into LDS once (histogram fused into the staging
//      read), per-bucket node counting-sort LDS->LDS, quarter-wave register
//      gather, epilogue out = proj(expmap0(relu(support))). ----
__global__ __launch_bounds__(1024, 8) void sortgather_kernel(
    const __half* __restrict__ hidden, const int2* __restrict__ csr,
    const int* __restrict__ gcount, float* __restrict__ out) {
    __shared__ int2 raw[CAP];          // 28,160 B, staged csr segment
    __shared__ int2 srt[CAP];          // 28,160 B, node-sorted descriptors
    __shared__ int cnt_a[NPB];
    __shared__ int start[NPB];
    __shared__ int cur[NPB];
    __shared__ int s_lo, s_cnt;
    const int t  = threadIdx.x;
    const int b  = blockIdx.x;

    if (t < NPB) cnt_a[t] = 0;
    if (t < 64) {
        // exclusive scan of gcount; pick out bbase[b] and gcount[b]
        int g[8]; int gsum = 0;
        #pragma unroll
        for (int k = 0; k < 8; ++k) { g[k] = gcount[t * 8 + k]; gsum += g[k]; }
        int gpre = gsum;
        #pragma unroll
        for (int m = 1; m < 64; m <<= 1) {
            int u = __shfl_up(gpre, m, 64);
            if (t >= m) gpre += u;
        }
        int run = gpre - gsum;                 // bbase[t*8]
        #pragma unroll
        for (int k = 0; k < 8; ++k) {
            int bb = t * 8 + k;
            if (bb == b) { s_lo = run; s_cnt = g[k]; }
            run += g[k];
        }
    }
    __syncthreads();
    const int lo  = s_lo;
    int ecnt = s_cnt;
    if (ecnt > CAP) ecnt = CAP;        // statistically unreachable guard

    for (int i = t; i < ecnt; i += 1024) {       // stage + fused histogram
        int2 e = csr[lo + i];
        raw[i] = e;
        atomicAdd(&cnt_a[((unsigned)e.x) >> 24], 1);
    }
    __syncthreads();
    if (t < 64) {
        const int lane = t;
        int c[4]; int sum = 0;
        #pragma unroll
        for (int k = 0; k < 4; ++k) {
            int bb = lane * 4 + k;
            c[k] = (bb < NPB) ? cnt_a[bb] : 0;
            sum += c[k];
        }
        int pre = sum;
        #pragma unroll
        for (int m = 1; m < 64; m <<= 1) {
            int u = __shfl_up(pre, m, 64);
            if (lane >= m) pre += u;
        }
        int run = pre - sum;
        #pragma unroll
        for (int k = 0; k < 4; ++k) {
            int bb = lane * 4 + k;
            if (bb < NPB) { start[bb] = run; cur[bb] = run; run += c[k]; }
        }
    }
    __syncthreads();
    for (int i = t; i < ecnt; i += 1024) {       // LDS -> LDS counting sort
        int2 e = raw[i];
        int p  = atomicAdd(&cur[((unsigned)e.x) >> 24], 1);
        srt[p] = e;
    }
    __syncthreads();

    const int lane = t & 63;
    const int wv   = t >> 6;               // 0..15
    const int g    = lane >> 4;
    const int l8   = (lane & 15) * 8;
    const char* __restrict__ hidc = (const char*)hidden;
    const float MIN_NORM = 1e-15f;
    const float MAX_N = 1.0f - 1e-5f;

    for (int n = wv; n < NPB; n += 16) {
        int i   = start[n];
        int rhi = i + cnt_a[n];
        float ax = 0.f, ay = 0.f, az = 0.f, aw = 0.f;

        for (; i + 16 <= rhi; i += 16) {         // 4 groups of 4 edges in flight
            int2 dA = srt[i + g];
            int2 dB = srt[i + 4 + g];
            int2 dC = srt[i + 8 + g];
            int2 dD = srt[i + 12 + g];
            unsigned oA = (((unsigned)dA.x) & 0xFFFFFFu) + l8;
            unsigned oB = (((unsigned)dB.x) & 0xFFFFFFu) + l8;
            unsigned oC = (((unsigned)dC.x) & 0xFFFFFFu) + l8;
            unsigned oD = (((unsigned)dD.x) & 0xFFFFFFu) + l8;
            uint2 hA = *(const uint2*)(hidc + oA);
            uint2 hB = *(const uint2*)(hidc + oB);
            uint2 hC = *(const uint2*)(hidc + oC);
            uint2 hD = *(const uint2*)(hidc + oD);
            float vA = __int_as_float(dA.y);
            float vB = __int_as_float(dB.y);
            float vC = __int_as_float(dC.y);
            float vD = __int_as_float(dD.y);
            ax = fmaf(vA, lo16f(hA.x), ax);
            ay = fmaf(vA, hi16f(hA.x), ay);
            az = fmaf(vA, lo16f(hA.y), az);
            aw = fmaf(vA, hi16f(hA.y), aw);
            ax = fmaf(vB, lo16f(hB.x), ax);
            ay = fmaf(vB, hi16f(hB.x), ay);
            az = fmaf(vB, lo16f(hB.y), az);
            aw = fmaf(vB, hi16f(hB.y), aw);
            ax = fmaf(vC, lo16f(hC.x), ax);
            ay = fmaf(vC, hi16f(hC.x), ay);
            az = fmaf(vC, lo16f(hC.y), az);
            aw = fmaf(vC, hi16f(hC.y), aw);
            ax = fmaf(vD, lo16f(hD.x), ax);
            ay = fmaf(vD, hi16f(hD.x), ay);
            az = fmaf(vD, lo16f(hD.y), az);
            aw = fmaf(vD, hi16f(hD.y), aw);
        }
        if (i + 8 <= rhi) {                      // 2 groups of 4 edges
            int2 dA = srt[i + g];
            int2 dB = srt[i + 4 + g];
            unsigned oA = (((unsigned)dA.x) & 0xFFFFFFu) + l8;
            unsigned oB = (((unsigned)dB.x) & 0xFFFFFFu) + l8;
            uint2 hA = *(const uint2*)(hidc + oA);
            uint2 hB = *(const uint2*)(hidc + oB);
            float vA = __int_as_float(dA.y);
            float vB = __int_as_float(dB.y);
            ax = fmaf(vA, lo16f(hA.x), ax);
            ay = fmaf(vA, hi16f(hA.x), ay);
            az = fmaf(vA, lo16f(hA.y), az);
            aw = fmaf(vA, hi16f(hA.y), aw);
            ax = fmaf(vB, lo16f(hB.x), ax);
            ay = fmaf(vB, hi16f(hB.x), ay);
            az = fmaf(vB, lo16f(hB.y), az);
            aw = fmaf(vB, hi16f(hB.y), aw);
            i += 8;
        }
        for (; i < rhi; i += 4) {                // masked 4-edge groups (<=2 iters)
            int idx = i + g;
            int2 d = srt[(idx < rhi) ? idx : (rhi - 1)];
            float v = (idx < rhi) ? __int_as_float(d.y) : 0.0f;
            unsigned o = (((unsigned)d.x) & 0xFFFFFFu) + l8;
            uint2 h = *(const uint2*)(hidc + o);
            ax = fmaf(v, lo16f(h.x), ax);
            ay = fmaf(v, hi16f(h.x), ay);
            az = fmaf(v, lo16f(h.y), az);
            aw = fmaf(v, hi16f(h.y), aw);
        }

        ax += __shfl_xor(ax, 16, 64); ax += __shfl_xor(ax, 32, 64);
        ay += __shfl_xor(ay, 16, 64); ay += __shfl_xor(ay, 32, 64);
        az += __shfl_xor(az, 16, 64); az += __shfl_xor(az, 32, 64);
        aw += __shfl_xor(aw, 16, 64); aw += __shfl_xor(aw, 32, 64);

        float xx = fmaxf(ax, 0.f), xy = fmaxf(ay, 0.f);
        float xz = fmaxf(az, 0.f), xw = fmaxf(aw, 0.f);

        float part = xx*xx + xy*xy + xz*xz + xw*xw;
        float xt_n = fmaxf(sqrtf(group16_reduce_sum(part)), MIN_NORM);
        float txt  = fast_tanh(xt_n);                 // = ||out||
        float s3   = txt * frcp(xt_n);
        if (txt > MAX_N) s3 = MAX_N * frcp(xt_n);     // proj (dormant, kept)
        float ox = xx*s3, oy = xy*s3, oz = xz*s3, ow = xw*s3;

        int gn = b * NPB + n;
        if (g == 0 && gn < NN) {
            float4 o4 = make_float4(ox, oy, oz, ow);
            *(float4*)(out + gn * DD + (lane & 15) * 4) = o4;
        }
    }
}

extern "C" void kernel_launch(void* const* d_in, const int* in_sizes, int n_in,
                              void* d_out, int out_size, void* d_ws, size_t ws_size,
                              hipStream_t stream) {
    const float* x    = (const float*)d_in[0];
    const float* W    = (const float*)d_in[1];
    const float* ev   = (const float*)d_in[2];
    const int*   rows = (const int*)d_in[3];
    const int*   cols = (const int*)d_in[4];
    float* out = (float*)d_out;

    char* ws = (char*)d_ws;
    __half* hidden = (__half*)ws;                 // 12,800,000 B
    int2*   csr    = (int2*)(ws + 12800000);      // 12,800,000 B
    int*    cnt    = (int*)(ws + 25600000);       //  1,048,576 B (512x512 counts)
    int*    woff   = (int*)(ws + 26648576);       //  1,048,576 B (per-chunk bucket offsets)
    int*    gcount = (int*)(ws + 27697152);       //      2,048 B
                                                  // total ~27.7 MB

    linear_count_kernel<<<NB, 1024, 0, stream>>>(x, W, rows, hidden, cnt);
    offset_kernel<<<NB / 8, 512, 0, stream>>>(cnt, woff, gcount);
    sort_scatter_kernel<<<NB, 1024, 0, stream>>>(rows, cols, ev, cnt, woff, gcount, csr);
    sortgather_kernel<<<NB, 1024, 0, stream>>>(hidden, csr, gcount, out);
}